// Round 17
// baseline (94.092 us; speedup 1.0000x reference)
//
#include <hip/hip_runtime.h>
#include <hip/hip_bf16.h>
#include <math.h>

// ---- problem constants ----
#define BSZ 32
#define SL 256
#define WPL 4
#define NP 320
#define WD 768
#define PD 64
#define RD 64
#define FD 512
#define PL 8
#define NF 128
#define ES_STRIDE 513    // 2*SL + 1
#define MROWS (BSZ * SL) // 8192
#define NZ 384           // 3 windows * NF
#define KZ 2048          // 4 * FD  (window-taps folded into K)

typedef __attribute__((ext_vector_type(8))) short bf16x8;
typedef __attribute__((ext_vector_type(4))) float f32x4;
typedef unsigned short ushort_t;
typedef __attribute__((ext_vector_type(4))) ushort_t u16x4;

__device__ __forceinline__ ushort_t f2bf(float x) {
    __hip_bfloat16 h = __float2bfloat16(x);
    return *reinterpret_cast<ushort_t*>(&h);
}
__device__ __forceinline__ float bf2f(ushort_t u) {
    return __uint_as_float(((unsigned)u) << 16);
}

// ============================================================
// K1 setup (single launch, block ranges)
// ============================================================
#define NB_GATHER MROWS
#define B_WW   NB_GATHER
#define NB_WW  384
#define B_TAB  (B_WW + NB_WW)
#define NB_TAB 42
#define B_WZT  (B_TAB + NB_TAB)
#define NB_WZT 576
#define B_PAD  (B_WZT + NB_WZT)
#define NB_PAD 2
#define B_UT   (B_PAD + NB_PAD)
#define NB_UT  258
#define NB_TOTAL (B_UT + NB_UT)

__global__ __launch_bounds__(256) void setup_kernel(
    const float* __restrict__ bert, const int* __restrict__ wgi,
    const int* __restrict__ pos, const int* __restrict__ path,
    const float* __restrict__ pos_emb, const float* __restrict__ pd_emb,
    const float* __restrict__ bilin_W, const float* __restrict__ deprel_emb,
    const float* __restrict__ ext_rel, const float* __restrict__ fc1_W,
    const float* __restrict__ fc1_b,
    const float* __restrict__ W2, const float* __restrict__ W3,
    const float* __restrict__ W4,
    ushort_t* __restrict__ word, int* __restrict__ depth,
    ushort_t* __restrict__ Ww, float* __restrict__ posc, float* __restrict__ pdc,
    ushort_t* __restrict__ WzT, ushort_t* __restrict__ node,
    float* __restrict__ Ut, float* __restrict__ v)
{
    const int tid = threadIdx.x;
    const int blk = blockIdx.x;
    if (blk < NB_GATHER) {
        const int bs = blk;
        const int b = bs >> 8;
        const int* gi = wgi + (size_t)bs * WPL;
        const int i0 = gi[0], i1 = gi[1], i2 = gi[2], i3 = gi[3];
        const int npc = (i0 != 0) + (i1 != 0) + (i2 != 0) + (i3 != 0);
        const float inv = 1.0f / (float)(npc > 1 ? npc : 1);
        if (tid < 192) {
            const float4* r0 = (const float4*)(bert + ((size_t)b * NP + (i0 - 1)) * WD);
            const float4* r1 = (const float4*)(bert + ((size_t)b * NP + (i1 - 1)) * WD);
            const float4* r2 = (const float4*)(bert + ((size_t)b * NP + (i2 - 1)) * WD);
            const float4* r3 = (const float4*)(bert + ((size_t)b * NP + (i3 - 1)) * WD);
            float4 s = make_float4(0.f, 0.f, 0.f, 0.f);
            if (i0) { float4 t = r0[tid]; s.x += t.x; s.y += t.y; s.z += t.z; s.w += t.w; }
            if (i1) { float4 t = r1[tid]; s.x += t.x; s.y += t.y; s.z += t.z; s.w += t.w; }
            if (i2) { float4 t = r2[tid]; s.x += t.x; s.y += t.y; s.z += t.z; s.w += t.w; }
            if (i3) { float4 t = r3[tid]; s.x += t.x; s.y += t.y; s.z += t.z; s.w += t.w; }
            u16x4 o;
            o[0] = f2bf(s.x * inv); o[1] = f2bf(s.y * inv);
            o[2] = f2bf(s.z * inv); o[3] = f2bf(s.w * inv);
            *reinterpret_cast<u16x4*>(&word[(size_t)bs * WD + tid * 4]) = o;
        } else if (tid == 192) {
            const int* pp = path + (size_t)bs * PL;
            int pd = 0;
#pragma unroll
            for (int l = 0; l < PL; ++l) pd += (pp[l] != 0);
            depth[bs] = pd;
        }
        return;
    }
    if (blk < B_TAB) {                 // Ww transpose (32x32 tiles)
        __shared__ float s[32][33];
        const int t = blk - B_WW;
        const int kt = t % 24, nt = t / 24;
#pragma unroll
        for (int i = 0; i < 4; ++i) {
            const int idx = i * 256 + tid;
            const int kk = idx >> 5, nn = idx & 31;
            s[kk][nn] = fc1_W[(size_t)(kt * 32 + kk) * FD + nt * 32 + nn];
        }
        __syncthreads();
#pragma unroll
        for (int i = 0; i < 4; ++i) {
            const int idx = i * 256 + tid;
            const int nn = idx >> 5, kk = idx & 31;
            Ww[(size_t)(nt * 32 + nn) * WD + kt * 32 + kk] = f2bf(s[kk][nn]);
        }
        return;
    }
    if (blk < B_WZT) {                 // posc / pdc tables
        const int r = blk - B_TAB;
#pragma unroll
        for (int h = 0; h < 2; ++h) {
            const int cc = tid + h * 256;
            if (r < 32) {
                float acc = fc1_b[cc];
#pragma unroll
                for (int j = 0; j < PD; ++j)
                    acc += pos_emb[r * PD + j] * fc1_W[(size_t)(WD + j) * FD + cc];
                posc[(size_t)r * FD + cc] = acc;
            } else {
                const int r2 = r - 32;
                float acc = 0.f;
#pragma unroll
                for (int j = 0; j < PD; ++j)
                    acc += pd_emb[r2 * PD + j] * fc1_W[(size_t)(WD + PD + j) * FD + cc];
                pdc[(size_t)r2 * FD + cc] = acc;
            }
        }
        return;
    }
    if (blk < B_PAD) {                 // WzT LDS-tiled transpose, only k<kw taps
        __shared__ float s[32][33];
        const int t2 = blk - B_WZT;
        const int p = t2 / 64, tt = t2 % 64;
        const int dt = tt & 15, ft = tt >> 4;
        int w, k; const float* src;
        if (p < 2)      { w = 0; k = p;     src = W2; }
        else if (p < 5) { w = 1; k = p - 2; src = W3; }
        else            { w = 2; k = p - 5; src = W4; }
#pragma unroll
        for (int i = 0; i < 4; ++i) {
            const int idx = i * 256 + tid;
            const int dd = idx >> 5, ff = idx & 31;
            s[dd][ff] = src[((size_t)k * FD + dt * 32 + dd) * NF + ft * 32 + ff];
        }
        __syncthreads();
#pragma unroll
        for (int i = 0; i < 4; ++i) {
            const int idx = i * 256 + tid;
            const int ff = idx >> 5, dd = idx & 31;
            WzT[(size_t)(w * NF + ft * 32 + ff) * KZ + k * FD + dt * 32 + dd] = f2bf(s[dd][ff]);
        }
        return;
    }
    if (blk < B_UT) {                  // node pad rows
        const int local = (blk - B_PAD) * 256 + tid;
#pragma unroll
        for (int j = 0; j < 3; ++j) node[(size_t)MROWS * FD + local * 3 + j] = 0;
        return;
    }
    {                                  // Ut and v
        const int idx = (blk - B_UT) * 256 + tid;
        if (idx < 65536) {
            const int r = idx >> 10, d = idx & 1023;
            float s = 0.f;
#pragma unroll
            for (int j = 0; j < RD; ++j) s += bilin_W[d * RD + j] * deprel_emb[r * RD + j];
            Ut[idx] = s;
        } else if (idx < 65536 + FD) {
            const int d = idx - 65536;
            float s = 0.f;
#pragma unroll
            for (int j = 0; j < RD; ++j) s += bilin_W[d * RD + j] * ext_rel[j];
            v[d] = s;
        }
        return;
    }
}

// ============================================================
// K2: node = relu(word @ Ww^T + posc[pos] + pdc[depth]).
// BM=64 x BN=64, BK=128 (6 K-steps), 2 waves (128 thr), wave 32x64.
// 16-chunk XOR swizzle (q ^= r&15) on src + read.  setprio around MFMA.
// 1D grid 1024 blocks = 4 blocks/CU, XCD-grouping swizzle.
// ============================================================
__global__ __launch_bounds__(128) void gemm_node(
    const ushort_t* __restrict__ A,   // word [M][768]
    const ushort_t* __restrict__ Bt,  // Ww [512][768]
    const int* __restrict__ pos, const int* __restrict__ depth,
    const float* __restrict__ posc, const float* __restrict__ pdc,
    ushort_t* __restrict__ C)         // [M][512]
{
    __shared__ ushort_t As[64 * 128];
    __shared__ ushort_t Bs[64 * 128];
    __shared__ int spos[64], sdep[64];
    const int tid = threadIdx.x;
    const int wid = tid >> 6, lane = tid & 63;
    const int orig = (blockIdx.x & 127) * 8 + (blockIdx.x >> 7);
    const int row0 = (orig >> 3) * 64, col0 = (orig & 7) * 64;
    const int lr = lane & 15, lk = lane >> 4;
    if (tid < 64) { spos[tid] = pos[row0 + tid]; sdep[tid] = depth[row0 + tid]; }
    f32x4 acc[2][4] = {};
    const ushort_t* gA0 = A + (size_t)row0 * WD;
    const ushort_t* gB0 = Bt + (size_t)col0 * WD;
    for (int k0 = 0; k0 < WD; k0 += 128) {
#pragma unroll
        for (int i = 0; i < 8; ++i) {
            const int c = i * 128 + tid;
            const int r = c >> 4, q = (c & 15) ^ (r & 15);
            __builtin_amdgcn_global_load_lds(
                (const __attribute__((address_space(1))) void*)(gA0 + (size_t)r * WD + k0 + q * 8),
                (__attribute__((address_space(3))) void*)((char*)As + (size_t)c * 16),
                16, 0, 0);
        }
#pragma unroll
        for (int i = 0; i < 8; ++i) {
            const int c = i * 128 + tid;
            const int r = c >> 4, q = (c & 15) ^ (r & 15);
            __builtin_amdgcn_global_load_lds(
                (const __attribute__((address_space(1))) void*)(gB0 + (size_t)r * WD + k0 + q * 8),
                (__attribute__((address_space(3))) void*)((char*)Bs + (size_t)c * 16),
                16, 0, 0);
        }
        __syncthreads();
        __builtin_amdgcn_s_setprio(1);
#pragma unroll
        for (int ks = 0; ks < 4; ++ks) {
            bf16x8 af[2], bfv[4];
#pragma unroll
            for (int m = 0; m < 2; ++m) {
                const int fr = wid * 32 + m * 16 + lr;
                af[m] = *reinterpret_cast<const bf16x8*>(
                    &As[fr * 128 + ((((ks << 2) | lk) ^ (fr & 15)) << 3)]);
            }
#pragma unroll
            for (int n = 0; n < 4; ++n) {
                const int fr = n * 16 + lr;
                bfv[n] = *reinterpret_cast<const bf16x8*>(
                    &Bs[fr * 128 + ((((ks << 2) | lk) ^ (fr & 15)) << 3)]);
            }
#pragma unroll
            for (int m = 0; m < 2; ++m)
#pragma unroll
                for (int n = 0; n < 4; ++n)
                    acc[m][n] = __builtin_amdgcn_mfma_f32_16x16x32_bf16(
                        af[m], bfv[n], acc[m][n], 0, 0, 0);
        }
        __builtin_amdgcn_s_setprio(0);
        __syncthreads();
    }
#pragma unroll
    for (int n = 0; n < 4; ++n) {
        const int col = col0 + n * 16 + lr;
#pragma unroll
        for (int m = 0; m < 2; ++m) {
            const f32x4 vv = acc[m][n];
#pragma unroll
            for (int j = 0; j < 4; ++j) {
                const int rloc = wid * 32 + m * 16 + lk * 4 + j;
                const float bv = posc[(size_t)spos[rloc] * FD + col]
                               + pdc[(size_t)sdep[rloc] * FD + col];
                C[(size_t)(row0 + rloc) * FD + col] = f2bf(fmaxf(vv[j] + bv, 0.f));
            }
        }
    }
}

// ============================================================
// K3: edge scores, PAIRED.  One 64-lane wave per n in [0,SL) computes
// BOTH edge n (dep.uc1 + node.uc2) and edge n+SL (node.v) from a single
// node-row load.  grid 2048 x 256 (4 waves/block).
// ============================================================
__global__ __launch_bounds__(256) void score_kernel(
    const ushort_t* __restrict__ node, const int* __restrict__ aspect_head,
    const int* __restrict__ deprel, const float* __restrict__ Ut,
    const float* __restrict__ v, const float* __restrict__ bilin_b,
    float* __restrict__ edge_score)
{
    const int g = blockIdx.x * 4 + (threadIdx.x >> 6);   // 0..8191
    const int lane = threadIdx.x & 63;
    const int b = g >> 8;
    const int n = g & 255;
    const int d0 = lane * 8;
    typedef __attribute__((ext_vector_type(8))) unsigned short u16x8;
    const int dr = deprel[b * SL + n];
    const int h = aspect_head[b * SL + n];
    const float* uc = Ut + (size_t)dr * 1024;
    const u16x8 nv = *reinterpret_cast<const u16x8*>(&node[((size_t)b * SL + n) * FD + d0]);
    float sum1 = 0.f, sum2 = 0.f;
    if (h != 0) {
        const u16x8 dv = *reinterpret_cast<const u16x8*>(&node[((size_t)b * SL + (h - 1)) * FD + d0]);
#pragma unroll
        for (int i = 0; i < 8; ++i) sum1 += bf2f(dv[i]) * uc[d0 + i];
    }
#pragma unroll
    for (int i = 0; i < 8; ++i) {
        const float nf = bf2f(nv[i]);
        sum1 += nf * uc[FD + d0 + i];
        sum2 += nf * v[d0 + i];
    }
#pragma unroll
    for (int off = 32; off > 0; off >>= 1) {
        sum1 += __shfl_xor(sum1, off, 64);
        sum2 += __shfl_xor(sum2, off, 64);
    }
    if (lane == 0) {
        const float bb = bilin_b[0];
        edge_score[b * ES_STRIDE + 1 + n] = 1.f / (1.f + expf(-(sum1 + bb)));
        edge_score[b * ES_STRIDE + 1 + SL + n] = 1.f / (1.f + expf(-(sum2 + bb)));
        if (n == 0) edge_score[b * ES_STRIDE] = 1.0f;
    }
}

// ============================================================
// K4: GEMM-Z + fused pool.  BM=64 x BN=64, BK=128, 2 waves (128 thr),
// wave 32x64.  1D grid 768 blocks = 3 blocks/CU, XCD swizzle.  setprio.
// nw recomputed inline from es + path + masks.
// Keff = (w+2)*512 skips zero taps.  pmaxp[256][NZ] partial maxes.
// ============================================================
__global__ __launch_bounds__(128) void gemm_z_pool(
    const ushort_t* __restrict__ node,  // [(MROWS+3)][FD] flat
    const ushort_t* __restrict__ WzT,   // [NZ][KZ]
    const float* __restrict__ es,       // [BSZ][ES_STRIDE]
    const int* __restrict__ path, const int* __restrict__ tmask,
    const int* __restrict__ amask,
    const float* __restrict__ b2, const float* __restrict__ b3,
    const float* __restrict__ b4,
    float* __restrict__ pmaxp)          // [256][NZ]
{
    __shared__ ushort_t As[64 * 128];
    __shared__ ushort_t Bs[64 * 128];
    __shared__ float ses[ES_STRIDE];
    __shared__ float snw[68];
    const int tid = threadIdx.x;
    const int wid = tid >> 6, lane = tid & 63;
    const int orig = (blockIdx.x % 96) * 8 + blockIdx.x / 96;
    const int ct = orig % 6, rt = orig / 6;   // col-tile 0..5, row-tile 0..127
    const int row0 = rt * 64, col0 = ct * 64;
    const int lr = lane & 15, lk = lane >> 4;
    f32x4 acc[2][4] = {};
    const ushort_t* gA0 = node + (size_t)row0 * FD;   // row-shift linear in flat idx
    const ushort_t* gB0 = WzT + (size_t)col0 * KZ;
    const int w = col0 >> 7;                  // window 0..2
    const int Keff = (w + 2) * 512;
    for (int k0 = 0; k0 < Keff; k0 += 128) {
#pragma unroll
        for (int i = 0; i < 8; ++i) {
            const int c = i * 128 + tid;
            const int r = c >> 4, q = (c & 15) ^ (r & 15);
            __builtin_amdgcn_global_load_lds(
                (const __attribute__((address_space(1))) void*)(gA0 + (size_t)r * FD + k0 + q * 8),
                (__attribute__((address_space(3))) void*)((char*)As + (size_t)c * 16),
                16, 0, 0);
        }
#pragma unroll
        for (int i = 0; i < 8; ++i) {
            const int c = i * 128 + tid;
            const int r = c >> 4, q = (c & 15) ^ (r & 15);
            __builtin_amdgcn_global_load_lds(
                (const __attribute__((address_space(1))) void*)(gB0 + (size_t)r * KZ + k0 + q * 8),
                (__attribute__((address_space(3))) void*)((char*)Bs + (size_t)c * 16),
                16, 0, 0);
        }
        __syncthreads();
        __builtin_amdgcn_s_setprio(1);
#pragma unroll
        for (int ks = 0; ks < 4; ++ks) {
            bf16x8 af[2], bfv[4];
#pragma unroll
            for (int m = 0; m < 2; ++m) {
                const int fr = wid * 32 + m * 16 + lr;
                af[m] = *reinterpret_cast<const bf16x8*>(
                    &As[fr * 128 + ((((ks << 2) | lk) ^ (fr & 15)) << 3)]);
            }
#pragma unroll
            for (int n = 0; n < 4; ++n) {
                const int fr = n * 16 + lr;
                bfv[n] = *reinterpret_cast<const bf16x8*>(
                    &Bs[fr * 128 + ((((ks << 2) | lk) ^ (fr & 15)) << 3)]);
            }
#pragma unroll
            for (int m = 0; m < 2; ++m)
#pragma unroll
                for (int n = 0; n < 4; ++n)
                    acc[m][n] = __builtin_amdgcn_mfma_f32_16x16x32_bf16(
                        af[m], bfv[n], acc[m][n], 0, 0, 0);
        }
        __builtin_amdgcn_s_setprio(0);
        __syncthreads();
    }
    // ---- inline nw from es + path + masks ----
    const int bI = row0 >> 8;
    const int nn0 = row0 & 255;
    const float* esb = es + (size_t)bI * ES_STRIDE;
    for (int i = tid; i < ES_STRIDE; i += 128) ses[i] = esb[i];
    __syncthreads();
    for (int i = tid; i < 68; i += 128) {
        const int s = nn0 + i;
        float p = 0.f;
        if (s < SL) {
            const int* pp = path + ((size_t)bI * SL + s) * PL;
            p = 1.f;
#pragma unroll
            for (int l = 0; l < PL; ++l) p *= ses[pp[l]];
            if (!(tmask[bI * SL + s] != 0 && amask[bI * SL + s] == 0)) p = 0.f;
        }
        snw[i] = p;
    }
    __syncthreads();
    // ---- fused pool epilogue ----
    const int kw = w + 2;
    const float invk = (w == 0) ? 0.5f : (w == 1) ? (1.f / 3.f) : 0.25f;
    const float* bias = (w == 0) ? b2 : (w == 1) ? b3 : b4;
    const int nmax = SL - kw;
    float cmax[4];
#pragma unroll
    for (int n = 0; n < 4; ++n) {
        const int col = col0 + n * 16 + lr;
        const float bf = bias[col & 127];
        float mx = -INFINITY;
#pragma unroll
        for (int m = 0; m < 2; ++m) {
            const int rbase = wid * 32 + m * 16 + lk * 4;
            const f32x4 vv = acc[m][n];
#pragma unroll
            for (int j = 0; j < 4; ++j) {
                const int rloc = rbase + j;
                if (nn0 + rloc <= nmax) {
                    float ws = 0.f;
                    for (int k = 0; k < kw; ++k) ws += snw[rloc + k];
                    mx = fmaxf(mx, ws * invk * vv[j] + bf);
                }
            }
        }
        mx = fmaxf(mx, __shfl_xor(mx, 16));
        mx = fmaxf(mx, __shfl_xor(mx, 32));
        cmax[n] = mx;
    }
    if (lane < 16) {
#pragma unroll
        for (int n = 0; n < 4; ++n) {
            const int col = col0 + n * 16 + lr;
            pmaxp[((size_t)rt * 2 + wid) * NZ + col] = cmax[n];
        }
    }
}

// ============================================================
// K5: finish: weight_norm[b] from es+path+masks; sentence = max over
// 8 partial rows; predicts = sentence @ fc_out_W + b.  grid BSZ x 384.
// ============================================================
__global__ __launch_bounds__(384) void finish_kernel(
    const float* __restrict__ pmaxp, const float* __restrict__ es,
    const int* __restrict__ path, const int* __restrict__ tmask,
    const int* __restrict__ amask,
    const float* __restrict__ W, const float* __restrict__ bias,
    float* __restrict__ out)
{
    __shared__ float ses[ES_STRIDE];
    __shared__ float sent[384];
    __shared__ float red[256];
    const int b = blockIdx.x;
    const int t = threadIdx.x;     // 0..383
    const float* esb = es + (size_t)b * ES_STRIDE;
    for (int i = t; i < ES_STRIDE; i += 384) ses[i] = esb[i];
    const float* p = pmaxp + (size_t)b * 8 * NZ + t;
    float mx = -INFINITY;
#pragma unroll
    for (int i = 0; i < 8; ++i) mx = fmaxf(mx, p[(size_t)i * NZ]);
    sent[t] = mx;
    __syncthreads();
    if (t < 256) {
        const int* pp = path + ((size_t)b * SL + t) * PL;
        float pr = 1.f;
#pragma unroll
        for (int l = 0; l < PL; ++l) pr *= ses[pp[l]];
        if (!(tmask[b * SL + t] != 0 && amask[b * SL + t] == 0)) pr = 0.f;
        red[t] = pr;
    }
    __syncthreads();
    for (int off = 128; off > 0; off >>= 1) {
        if (t < off) red[t] += red[t + off];
        __syncthreads();
    }
    if (t == 0) out[96 + b] = red[0];
    if (t < 3) {
        float acc = bias[t];
        for (int i = 0; i < 384; ++i) acc = fmaf(sent[i], W[i * 3 + t], acc);
        out[b * 3 + t] = acc;
    }
}

// ============================================================
extern "C" void kernel_launch(void* const* d_in, const int* in_sizes, int n_in,
                              void* d_out, int out_size, void* d_ws, size_t ws_size,
                              hipStream_t stream)
{
    const float* bert      = (const float*)d_in[0];
    const int*   wgi       = (const int*)d_in[1];
    const int*   pos       = (const int*)d_in[2];
    const int*   deprel    = (const int*)d_in[3];
    const int*   path      = (const int*)d_in[4];
    const int*   ahead     = (const int*)d_in[5];
    const int*   tmask     = (const int*)d_in[6];
    const int*   amask     = (const int*)d_in[7];
    const float* pos_emb   = (const float*)d_in[8];
    const float* dre_emb   = (const float*)d_in[9];
    const float* pd_emb    = (const float*)d_in[10];
    const float* ext_rel   = (const float*)d_in[11];
    const float* fc1_W     = (const float*)d_in[12];
    const float* fc1_b     = (const float*)d_in[13];
    const float* bilin_W   = (const float*)d_in[14];
    const float* bilin_b   = (const float*)d_in[15];
    const float* W2        = (const float*)d_in[16];
    const float* b2        = (const float*)d_in[17];
    const float* W3        = (const float*)d_in[18];
    const float* b3        = (const float*)d_in[19];
    const float* W4        = (const float*)d_in[20];
    const float* b4        = (const float*)d_in[21];
    const float* fco_W     = (const float*)d_in[22];
    const float* fco_b     = (const float*)d_in[23];
    float* out = (float*)d_out;

    // ---- workspace layout ----
    uint8_t* w = (uint8_t*)d_ws;
    size_t off = 0;
    ushort_t* word = (ushort_t*)(w + off); off += (size_t)MROWS * WD * 2;       // 12.6MB
    ushort_t* node = (ushort_t*)(w + off); off += (size_t)(MROWS + 3) * FD * 2; // 8.4MB
    ushort_t* Ww   = (ushort_t*)(w + off); off += (size_t)FD * WD * 2;          // 0.79MB
    ushort_t* WzT  = (ushort_t*)(w + off); off += (size_t)NZ * KZ * 2;          // 1.57MB
    float* Ut    = (float*)(w + off); off += (size_t)64 * 1024 * 4;
    float* vvec  = (float*)(w + off); off += FD * 4;
    float* posc  = (float*)(w + off); off += (size_t)32 * FD * 4;
    float* pdc   = (float*)(w + off); off += (size_t)10 * FD * 4;
    float* es    = (float*)(w + off); off += (size_t)BSZ * ES_STRIDE * 4;
    float* pmaxp = (float*)(w + off); off += (size_t)256 * NZ * 4;
    int*   depth = (int*)(w + off);  off += (size_t)MROWS * 4;

    setup_kernel<<<NB_TOTAL, 256, 0, stream>>>(
        bert, wgi, pos, path, pos_emb, pd_emb,
        bilin_W, dre_emb, ext_rel, fc1_W, fc1_b, W2, W3, W4,
        word, depth, Ww, posc, pdc, WzT, node, Ut, vvec);

    gemm_node<<<1024, 128, 0, stream>>>(
        word, Ww, pos, depth, posc, pdc, node);

    score_kernel<<<(BSZ * SL) / 4, 256, 0, stream>>>(
        node, ahead, deprel, Ut, vvec, bilin_b, es);

    gemm_z_pool<<<768, 128, 0, stream>>>(
        node, WzT, es, path, tmask, amask, b2, b3, b4, pmaxp);

    finish_kernel<<<BSZ, 384, 0, stream>>>(
        pmaxp, es, path, tmask, amask, fco_W, fco_b, out);
}

// Round 18
// 90.340 us; speedup vs baseline: 1.0415x; 1.0415x over previous
//
#include <hip/hip_runtime.h>
#include <hip/hip_bf16.h>
#include <math.h>

// ---- problem constants ----
#define BSZ 32
#define SL 256
#define WPL 4
#define NP 320
#define WD 768
#define PD 64
#define RD 64
#define FD 512
#define PL 8
#define NF 128
#define ES_STRIDE 513    // 2*SL + 1
#define MROWS (BSZ * SL) // 8192
#define NZ 384           // 3 windows * NF
#define KZ 2048          // 4 * FD  (window-taps folded into K)

typedef __attribute__((ext_vector_type(8))) short bf16x8;
typedef __attribute__((ext_vector_type(4))) float f32x4;
typedef unsigned short ushort_t;
typedef __attribute__((ext_vector_type(4))) ushort_t u16x4;

__device__ __forceinline__ ushort_t f2bf(float x) {
    __hip_bfloat16 h = __float2bfloat16(x);
    return *reinterpret_cast<ushort_t*>(&h);
}
__device__ __forceinline__ float bf2f(ushort_t u) {
    return __uint_as_float(((unsigned)u) << 16);
}

// ============================================================
// K1 setup (single launch, block ranges)
// ============================================================
#define NB_GATHER MROWS
#define B_WW   NB_GATHER
#define NB_WW  384
#define B_TAB  (B_WW + NB_WW)
#define NB_TAB 42
#define B_WZT  (B_TAB + NB_TAB)
#define NB_WZT 576
#define B_PAD  (B_WZT + NB_WZT)
#define NB_PAD 2
#define B_UT   (B_PAD + NB_PAD)
#define NB_UT  258
#define NB_TOTAL (B_UT + NB_UT)

__global__ __launch_bounds__(256) void setup_kernel(
    const float* __restrict__ bert, const int* __restrict__ wgi,
    const int* __restrict__ pos, const int* __restrict__ path,
    const float* __restrict__ pos_emb, const float* __restrict__ pd_emb,
    const float* __restrict__ bilin_W, const float* __restrict__ deprel_emb,
    const float* __restrict__ ext_rel, const float* __restrict__ fc1_W,
    const float* __restrict__ fc1_b,
    const float* __restrict__ W2, const float* __restrict__ W3,
    const float* __restrict__ W4,
    ushort_t* __restrict__ word, int* __restrict__ depth,
    ushort_t* __restrict__ Ww, float* __restrict__ posc, float* __restrict__ pdc,
    ushort_t* __restrict__ WzT, ushort_t* __restrict__ node,
    float* __restrict__ Ut, float* __restrict__ v)
{
    const int tid = threadIdx.x;
    const int blk = blockIdx.x;
    if (blk < NB_GATHER) {
        const int bs = blk;
        const int b = bs >> 8;
        const int* gi = wgi + (size_t)bs * WPL;
        const int i0 = gi[0], i1 = gi[1], i2 = gi[2], i3 = gi[3];
        const int npc = (i0 != 0) + (i1 != 0) + (i2 != 0) + (i3 != 0);
        const float inv = 1.0f / (float)(npc > 1 ? npc : 1);
        if (tid < 192) {
            const float4* r0 = (const float4*)(bert + ((size_t)b * NP + (i0 - 1)) * WD);
            const float4* r1 = (const float4*)(bert + ((size_t)b * NP + (i1 - 1)) * WD);
            const float4* r2 = (const float4*)(bert + ((size_t)b * NP + (i2 - 1)) * WD);
            const float4* r3 = (const float4*)(bert + ((size_t)b * NP + (i3 - 1)) * WD);
            float4 s = make_float4(0.f, 0.f, 0.f, 0.f);
            if (i0) { float4 t = r0[tid]; s.x += t.x; s.y += t.y; s.z += t.z; s.w += t.w; }
            if (i1) { float4 t = r1[tid]; s.x += t.x; s.y += t.y; s.z += t.z; s.w += t.w; }
            if (i2) { float4 t = r2[tid]; s.x += t.x; s.y += t.y; s.z += t.z; s.w += t.w; }
            if (i3) { float4 t = r3[tid]; s.x += t.x; s.y += t.y; s.z += t.z; s.w += t.w; }
            u16x4 o;
            o[0] = f2bf(s.x * inv); o[1] = f2bf(s.y * inv);
            o[2] = f2bf(s.z * inv); o[3] = f2bf(s.w * inv);
            *reinterpret_cast<u16x4*>(&word[(size_t)bs * WD + tid * 4]) = o;
        } else if (tid == 192) {
            const int* pp = path + (size_t)bs * PL;
            int pd = 0;
#pragma unroll
            for (int l = 0; l < PL; ++l) pd += (pp[l] != 0);
            depth[bs] = pd;
        }
        return;
    }
    if (blk < B_TAB) {                 // Ww transpose (32x32 tiles)
        __shared__ float s[32][33];
        const int t = blk - B_WW;
        const int kt = t % 24, nt = t / 24;
#pragma unroll
        for (int i = 0; i < 4; ++i) {
            const int idx = i * 256 + tid;
            const int kk = idx >> 5, nn = idx & 31;
            s[kk][nn] = fc1_W[(size_t)(kt * 32 + kk) * FD + nt * 32 + nn];
        }
        __syncthreads();
#pragma unroll
        for (int i = 0; i < 4; ++i) {
            const int idx = i * 256 + tid;
            const int nn = idx >> 5, kk = idx & 31;
            Ww[(size_t)(nt * 32 + nn) * WD + kt * 32 + kk] = f2bf(s[kk][nn]);
        }
        return;
    }
    if (blk < B_WZT) {                 // posc / pdc tables
        const int r = blk - B_TAB;
#pragma unroll
        for (int h = 0; h < 2; ++h) {
            const int cc = tid + h * 256;
            if (r < 32) {
                float acc = fc1_b[cc];
#pragma unroll
                for (int j = 0; j < PD; ++j)
                    acc += pos_emb[r * PD + j] * fc1_W[(size_t)(WD + j) * FD + cc];
                posc[(size_t)r * FD + cc] = acc;
            } else {
                const int r2 = r - 32;
                float acc = 0.f;
#pragma unroll
                for (int j = 0; j < PD; ++j)
                    acc += pd_emb[r2 * PD + j] * fc1_W[(size_t)(WD + PD + j) * FD + cc];
                pdc[(size_t)r2 * FD + cc] = acc;
            }
        }
        return;
    }
    if (blk < B_PAD) {                 // WzT LDS-tiled transpose, only k<kw taps
        __shared__ float s[32][33];
        const int t2 = blk - B_WZT;
        const int p = t2 / 64, tt = t2 % 64;
        const int dt = tt & 15, ft = tt >> 4;
        int w, k; const float* src;
        if (p < 2)      { w = 0; k = p;     src = W2; }
        else if (p < 5) { w = 1; k = p - 2; src = W3; }
        else            { w = 2; k = p - 5; src = W4; }
#pragma unroll
        for (int i = 0; i < 4; ++i) {
            const int idx = i * 256 + tid;
            const int dd = idx >> 5, ff = idx & 31;
            s[dd][ff] = src[((size_t)k * FD + dt * 32 + dd) * NF + ft * 32 + ff];
        }
        __syncthreads();
#pragma unroll
        for (int i = 0; i < 4; ++i) {
            const int idx = i * 256 + tid;
            const int ff = idx >> 5, dd = idx & 31;
            WzT[(size_t)(w * NF + ft * 32 + ff) * KZ + k * FD + dt * 32 + dd] = f2bf(s[dd][ff]);
        }
        return;
    }
    if (blk < B_UT) {                  // node pad rows
        const int local = (blk - B_PAD) * 256 + tid;
#pragma unroll
        for (int j = 0; j < 3; ++j) node[(size_t)MROWS * FD + local * 3 + j] = 0;
        return;
    }
    {                                  // Ut and v
        const int idx = (blk - B_UT) * 256 + tid;
        if (idx < 65536) {
            const int r = idx >> 10, d = idx & 1023;
            float s = 0.f;
#pragma unroll
            for (int j = 0; j < RD; ++j) s += bilin_W[d * RD + j] * deprel_emb[r * RD + j];
            Ut[idx] = s;
        } else if (idx < 65536 + FD) {
            const int d = idx - 65536;
            float s = 0.f;
#pragma unroll
            for (int j = 0; j < RD; ++j) s += bilin_W[d * RD + j] * ext_rel[j];
            v[d] = s;
        }
        return;
    }
}

// ============================================================
// K2: node = relu(word @ Ww^T + posc[pos] + pdc[depth]).
// BM=64 x BN=64, BK=128 (6 K-steps), 2 waves (128 thr), wave 32x64.
// 16-chunk XOR swizzle (q ^= r&15) on src + read.  setprio around MFMA.
// 1D grid 1024 blocks = 4 blocks/CU, XCD-grouping swizzle.
// ============================================================
__global__ __launch_bounds__(128) void gemm_node(
    const ushort_t* __restrict__ A,   // word [M][768]
    const ushort_t* __restrict__ Bt,  // Ww [512][768]
    const int* __restrict__ pos, const int* __restrict__ depth,
    const float* __restrict__ posc, const float* __restrict__ pdc,
    ushort_t* __restrict__ C)         // [M][512]
{
    __shared__ ushort_t As[64 * 128];
    __shared__ ushort_t Bs[64 * 128];
    __shared__ int spos[64], sdep[64];
    const int tid = threadIdx.x;
    const int wid = tid >> 6, lane = tid & 63;
    const int orig = (blockIdx.x & 127) * 8 + (blockIdx.x >> 7);
    const int row0 = (orig >> 3) * 64, col0 = (orig & 7) * 64;
    const int lr = lane & 15, lk = lane >> 4;
    if (tid < 64) { spos[tid] = pos[row0 + tid]; sdep[tid] = depth[row0 + tid]; }
    f32x4 acc[2][4] = {};
    const ushort_t* gA0 = A + (size_t)row0 * WD;
    const ushort_t* gB0 = Bt + (size_t)col0 * WD;
    for (int k0 = 0; k0 < WD; k0 += 128) {
#pragma unroll
        for (int i = 0; i < 8; ++i) {
            const int c = i * 128 + tid;
            const int r = c >> 4, q = (c & 15) ^ (r & 15);
            __builtin_amdgcn_global_load_lds(
                (const __attribute__((address_space(1))) void*)(gA0 + (size_t)r * WD + k0 + q * 8),
                (__attribute__((address_space(3))) void*)((char*)As + (size_t)c * 16),
                16, 0, 0);
        }
#pragma unroll
        for (int i = 0; i < 8; ++i) {
            const int c = i * 128 + tid;
            const int r = c >> 4, q = (c & 15) ^ (r & 15);
            __builtin_amdgcn_global_load_lds(
                (const __attribute__((address_space(1))) void*)(gB0 + (size_t)r * WD + k0 + q * 8),
                (__attribute__((address_space(3))) void*)((char*)Bs + (size_t)c * 16),
                16, 0, 0);
        }
        __syncthreads();
        __builtin_amdgcn_s_setprio(1);
#pragma unroll
        for (int ks = 0; ks < 4; ++ks) {
            bf16x8 af[2], bfv[4];
#pragma unroll
            for (int m = 0; m < 2; ++m) {
                const int fr = wid * 32 + m * 16 + lr;
                af[m] = *reinterpret_cast<const bf16x8*>(
                    &As[fr * 128 + ((((ks << 2) | lk) ^ (fr & 15)) << 3)]);
            }
#pragma unroll
            for (int n = 0; n < 4; ++n) {
                const int fr = n * 16 + lr;
                bfv[n] = *reinterpret_cast<const bf16x8*>(
                    &Bs[fr * 128 + ((((ks << 2) | lk) ^ (fr & 15)) << 3)]);
            }
#pragma unroll
            for (int m = 0; m < 2; ++m)
#pragma unroll
                for (int n = 0; n < 4; ++n)
                    acc[m][n] = __builtin_amdgcn_mfma_f32_16x16x32_bf16(
                        af[m], bfv[n], acc[m][n], 0, 0, 0);
        }
        __builtin_amdgcn_s_setprio(0);
        __syncthreads();
    }
#pragma unroll
    for (int n = 0; n < 4; ++n) {
        const int col = col0 + n * 16 + lr;
#pragma unroll
        for (int m = 0; m < 2; ++m) {
            const f32x4 vv = acc[m][n];
#pragma unroll
            for (int j = 0; j < 4; ++j) {
                const int rloc = wid * 32 + m * 16 + lk * 4 + j;
                const float bv = posc[(size_t)spos[rloc] * FD + col]
                               + pdc[(size_t)sdep[rloc] * FD + col];
                C[(size_t)(row0 + rloc) * FD + col] = f2bf(fmaxf(vv[j] + bv, 0.f));
            }
        }
    }
}

// ============================================================
// K3: edge scores. One 64-lane wave per (b, n).  grid 4096 x 256.
// ============================================================
__global__ __launch_bounds__(256) void score_kernel(
    const ushort_t* __restrict__ node, const int* __restrict__ aspect_head,
    const int* __restrict__ deprel, const float* __restrict__ Ut,
    const float* __restrict__ v, const float* __restrict__ bilin_b,
    float* __restrict__ edge_score)
{
    const int g = blockIdx.x * 4 + (threadIdx.x >> 6);
    const int lane = threadIdx.x & 63;
    const int b = g >> 9;
    const int n = g & 511;
    const int d0 = lane * 8;
    typedef __attribute__((ext_vector_type(8))) unsigned short u16x8;
    float sum = 0.f;
    if (n < SL) {
        const int dr = deprel[b * SL + n];
        const int h = aspect_head[b * SL + n];
        const float* uc = Ut + (size_t)dr * 1024;
        const u16x8 nv = *reinterpret_cast<const u16x8*>(&node[((size_t)b * SL + n) * FD + d0]);
        if (h != 0) {
            const u16x8 dv = *reinterpret_cast<const u16x8*>(&node[((size_t)b * SL + (h - 1)) * FD + d0]);
#pragma unroll
            for (int i = 0; i < 8; ++i) sum += bf2f(dv[i]) * uc[d0 + i];
        }
#pragma unroll
        for (int i = 0; i < 8; ++i) sum += bf2f(nv[i]) * uc[FD + d0 + i];
    } else {
        const u16x8 nv = *reinterpret_cast<const u16x8*>(&node[((size_t)b * SL + (n - SL)) * FD + d0]);
#pragma unroll
        for (int i = 0; i < 8; ++i) sum += bf2f(nv[i]) * v[d0 + i];
    }
#pragma unroll
    for (int off = 32; off > 0; off >>= 1) sum += __shfl_xor(sum, off, 64);
    if (lane == 0) {
        const float sc = 1.f / (1.f + expf(-(sum + bilin_b[0])));
        edge_score[b * ES_STRIDE + 1 + n] = sc;
        if (n == 0) edge_score[b * ES_STRIDE] = 1.0f;
    }
}

// ============================================================
// K4: GEMM-Z + fused pool.  BM=64 x BN=64, BK=128, 2 waves (128 thr),
// wave 32x64.  1D grid 768 blocks = 3 blocks/CU, XCD swizzle.  setprio.
// nw recomputed inline from es + path + masks.
// Keff = (w+2)*512 skips zero taps.  pmaxp[256][NZ] partial maxes.
// ============================================================
__global__ __launch_bounds__(128) void gemm_z_pool(
    const ushort_t* __restrict__ node,  // [(MROWS+3)][FD] flat
    const ushort_t* __restrict__ WzT,   // [NZ][KZ]
    const float* __restrict__ es,       // [BSZ][ES_STRIDE]
    const int* __restrict__ path, const int* __restrict__ tmask,
    const int* __restrict__ amask,
    const float* __restrict__ b2, const float* __restrict__ b3,
    const float* __restrict__ b4,
    float* __restrict__ pmaxp)          // [256][NZ]
{
    __shared__ ushort_t As[64 * 128];
    __shared__ ushort_t Bs[64 * 128];
    __shared__ float ses[ES_STRIDE];
    __shared__ float snw[68];
    const int tid = threadIdx.x;
    const int wid = tid >> 6, lane = tid & 63;
    const int orig = (blockIdx.x % 96) * 8 + blockIdx.x / 96;
    const int ct = orig % 6, rt = orig / 6;   // col-tile 0..5, row-tile 0..127
    const int row0 = rt * 64, col0 = ct * 64;
    const int lr = lane & 15, lk = lane >> 4;
    f32x4 acc[2][4] = {};
    const ushort_t* gA0 = node + (size_t)row0 * FD;   // row-shift linear in flat idx
    const ushort_t* gB0 = WzT + (size_t)col0 * KZ;
    const int w = col0 >> 7;                  // window 0..2
    const int Keff = (w + 2) * 512;
    for (int k0 = 0; k0 < Keff; k0 += 128) {
#pragma unroll
        for (int i = 0; i < 8; ++i) {
            const int c = i * 128 + tid;
            const int r = c >> 4, q = (c & 15) ^ (r & 15);
            __builtin_amdgcn_global_load_lds(
                (const __attribute__((address_space(1))) void*)(gA0 + (size_t)r * FD + k0 + q * 8),
                (__attribute__((address_space(3))) void*)((char*)As + (size_t)c * 16),
                16, 0, 0);
        }
#pragma unroll
        for (int i = 0; i < 8; ++i) {
            const int c = i * 128 + tid;
            const int r = c >> 4, q = (c & 15) ^ (r & 15);
            __builtin_amdgcn_global_load_lds(
                (const __attribute__((address_space(1))) void*)(gB0 + (size_t)r * KZ + k0 + q * 8),
                (__attribute__((address_space(3))) void*)((char*)Bs + (size_t)c * 16),
                16, 0, 0);
        }
        __syncthreads();
        __builtin_amdgcn_s_setprio(1);
#pragma unroll
        for (int ks = 0; ks < 4; ++ks) {
            bf16x8 af[2], bfv[4];
#pragma unroll
            for (int m = 0; m < 2; ++m) {
                const int fr = wid * 32 + m * 16 + lr;
                af[m] = *reinterpret_cast<const bf16x8*>(
                    &As[fr * 128 + ((((ks << 2) | lk) ^ (fr & 15)) << 3)]);
            }
#pragma unroll
            for (int n = 0; n < 4; ++n) {
                const int fr = n * 16 + lr;
                bfv[n] = *reinterpret_cast<const bf16x8*>(
                    &Bs[fr * 128 + ((((ks << 2) | lk) ^ (fr & 15)) << 3)]);
            }
#pragma unroll
            for (int m = 0; m < 2; ++m)
#pragma unroll
                for (int n = 0; n < 4; ++n)
                    acc[m][n] = __builtin_amdgcn_mfma_f32_16x16x32_bf16(
                        af[m], bfv[n], acc[m][n], 0, 0, 0);
        }
        __builtin_amdgcn_s_setprio(0);
        __syncthreads();
    }
    // ---- inline nw from es + path + masks ----
    const int bI = row0 >> 8;
    const int nn0 = row0 & 255;
    const float* esb = es + (size_t)bI * ES_STRIDE;
    for (int i = tid; i < ES_STRIDE; i += 128) ses[i] = esb[i];
    __syncthreads();
    for (int i = tid; i < 68; i += 128) {
        const int s = nn0 + i;
        float p = 0.f;
        if (s < SL) {
            const int* pp = path + ((size_t)bI * SL + s) * PL;
            p = 1.f;
#pragma unroll
            for (int l = 0; l < PL; ++l) p *= ses[pp[l]];
            if (!(tmask[bI * SL + s] != 0 && amask[bI * SL + s] == 0)) p = 0.f;
        }
        snw[i] = p;
    }
    __syncthreads();
    // ---- fused pool epilogue ----
    const int kw = w + 2;
    const float invk = (w == 0) ? 0.5f : (w == 1) ? (1.f / 3.f) : 0.25f;
    const float* bias = (w == 0) ? b2 : (w == 1) ? b3 : b4;
    const int nmax = SL - kw;
    float cmax[4];
#pragma unroll
    for (int n = 0; n < 4; ++n) {
        const int col = col0 + n * 16 + lr;
        const float bf = bias[col & 127];
        float mx = -INFINITY;
#pragma unroll
        for (int m = 0; m < 2; ++m) {
            const int rbase = wid * 32 + m * 16 + lk * 4;
            const f32x4 vv = acc[m][n];
#pragma unroll
            for (int j = 0; j < 4; ++j) {
                const int rloc = rbase + j;
                if (nn0 + rloc <= nmax) {
                    float ws = 0.f;
                    for (int k = 0; k < kw; ++k) ws += snw[rloc + k];
                    mx = fmaxf(mx, ws * invk * vv[j] + bf);
                }
            }
        }
        mx = fmaxf(mx, __shfl_xor(mx, 16));
        mx = fmaxf(mx, __shfl_xor(mx, 32));
        cmax[n] = mx;
    }
    if (lane < 16) {
#pragma unroll
        for (int n = 0; n < 4; ++n) {
            const int col = col0 + n * 16 + lr;
            pmaxp[((size_t)rt * 2 + wid) * NZ + col] = cmax[n];
        }
    }
}

// ============================================================
// K5: finish: weight_norm[b] from es+path+masks; sentence = max over
// 8 partial rows; predicts = sentence @ fc_out_W + b.  grid BSZ x 384.
// ============================================================
__global__ __launch_bounds__(384) void finish_kernel(
    const float* __restrict__ pmaxp, const float* __restrict__ es,
    const int* __restrict__ path, const int* __restrict__ tmask,
    const int* __restrict__ amask,
    const float* __restrict__ W, const float* __restrict__ bias,
    float* __restrict__ out)
{
    __shared__ float ses[ES_STRIDE];
    __shared__ float sent[384];
    __shared__ float red[256];
    const int b = blockIdx.x;
    const int t = threadIdx.x;     // 0..383
    const float* esb = es + (size_t)b * ES_STRIDE;
    for (int i = t; i < ES_STRIDE; i += 384) ses[i] = esb[i];
    const float* p = pmaxp + (size_t)b * 8 * NZ + t;
    float mx = -INFINITY;
#pragma unroll
    for (int i = 0; i < 8; ++i) mx = fmaxf(mx, p[(size_t)i * NZ]);
    sent[t] = mx;
    __syncthreads();
    if (t < 256) {
        const int* pp = path + ((size_t)b * SL + t) * PL;
        float pr = 1.f;
#pragma unroll
        for (int l = 0; l < PL; ++l) pr *= ses[pp[l]];
        if (!(tmask[b * SL + t] != 0 && amask[b * SL + t] == 0)) pr = 0.f;
        red[t] = pr;
    }
    __syncthreads();
    for (int off = 128; off > 0; off >>= 1) {
        if (t < off) red[t] += red[t + off];
        __syncthreads();
    }
    if (t == 0) out[96 + b] = red[0];
    if (t < 3) {
        float acc = bias[t];
        for (int i = 0; i < 384; ++i) acc = fmaf(sent[i], W[i * 3 + t], acc);
        out[b * 3 + t] = acc;
    }
}

// ============================================================
extern "C" void kernel_launch(void* const* d_in, const int* in_sizes, int n_in,
                              void* d_out, int out_size, void* d_ws, size_t ws_size,
                              hipStream_t stream)
{
    const float* bert      = (const float*)d_in[0];
    const int*   wgi       = (const int*)d_in[1];
    const int*   pos       = (const int*)d_in[2];
    const int*   deprel    = (const int*)d_in[3];
    const int*   path      = (const int*)d_in[4];
    const int*   ahead     = (const int*)d_in[5];
    const int*   tmask     = (const int*)d_in[6];
    const int*   amask     = (const int*)d_in[7];
    const float* pos_emb   = (const float*)d_in[8];
    const float* dre_emb   = (const float*)d_in[9];
    const float* pd_emb    = (const float*)d_in[10];
    const float* ext_rel   = (const float*)d_in[11];
    const float* fc1_W     = (const float*)d_in[12];
    const float* fc1_b     = (const float*)d_in[13];
    const float* bilin_W   = (const float*)d_in[14];
    const float* bilin_b   = (const float*)d_in[15];
    const float* W2        = (const float*)d_in[16];
    const float* b2        = (const float*)d_in[17];
    const float* W3        = (const float*)d_in[18];
    const float* b3        = (const float*)d_in[19];
    const float* W4        = (const float*)d_in[20];
    const float* b4        = (const float*)d_in[21];
    const float* fco_W     = (const float*)d_in[22];
    const float* fco_b     = (const float*)d_in[23];
    float* out = (float*)d_out;

    // ---- workspace layout ----
    uint8_t* w = (uint8_t*)d_ws;
    size_t off = 0;
    ushort_t* word = (ushort_t*)(w + off); off += (size_t)MROWS * WD * 2;       // 12.6MB
    ushort_t* node = (ushort_t*)(w + off); off += (size_t)(MROWS + 3) * FD * 2; // 8.4MB
    ushort_t* Ww   = (ushort_t*)(w + off); off += (size_t)FD * WD * 2;          // 0.79MB
    ushort_t* WzT  = (ushort_t*)(w + off); off += (size_t)NZ * KZ * 2;          // 1.57MB
    float* Ut    = (float*)(w + off); off += (size_t)64 * 1024 * 4;
    float* vvec  = (float*)(w + off); off += FD * 4;
    float* posc  = (float*)(w + off); off += (size_t)32 * FD * 4;
    float* pdc   = (float*)(w + off); off += (size_t)10 * FD * 4;
    float* es    = (float*)(w + off); off += (size_t)BSZ * ES_STRIDE * 4;
    float* pmaxp = (float*)(w + off); off += (size_t)256 * NZ * 4;
    int*   depth = (int*)(w + off);  off += (size_t)MROWS * 4;

    setup_kernel<<<NB_TOTAL, 256, 0, stream>>>(
        bert, wgi, pos, path, pos_emb, pd_emb,
        bilin_W, dre_emb, ext_rel, fc1_W, fc1_b, W2, W3, W4,
        word, depth, Ww, posc, pdc, WzT, node, Ut, vvec);

    gemm_node<<<1024, 128, 0, stream>>>(
        word, Ww, pos, depth, posc, pdc, node);

    score_kernel<<<(BSZ * 2 * SL) / 4, 256, 0, stream>>>(
        node, ahead, deprel, Ut, vvec, bilin_b, es);

    gemm_z_pool<<<768, 128, 0, stream>>>(
        node, WzT, es, path, tmask, amask, b2, b3, b4, pmaxp);

    finish_kernel<<<BSZ, 384, 0, stream>>>(
        pmaxp, es, path, tmask, amask, fco_W, fco_b, out);
}